// Round 4
// baseline (128.357 us; speedup 1.0000x reference)
//
#include <hip/hip_runtime.h>
#include <hip/hip_bf16.h>

// TripletBatchHardLoss: N=8192, D=256, fp32 embeddings (L2-normalized), int32 labels.
// Normalized -> pdist monotone DECREASING in dot:
//   hard_negative = max dot over negs, hard_positive = min dot over poss (diag dot~1 safe).
// Symmetric dot matrix: upper-triangle 128x128 blocks only (2080); each block reduces
// BOTH row-side and col-side.
// R4 structure: barrier-free K-loop. Full A-strip (128x256 = 64 KB) staged to LDS once
// (16 global_load_lds per wave + ONE __syncthreads); B-frags streamed from global
// (L1/L2-resident), manually double-buffered one kt ahead. No barriers in the K-loop ->
// waves pipeline independently instead of collectively draining vmcnt(0) 16x per block.

#define NS 8192
#define DD 256
#define EPS_PD 1e-12f
#define BIGF 1e30f

typedef unsigned short u16;
typedef unsigned int u32;
typedef short short8 __attribute__((ext_vector_type(8)));
typedef float f32x4 __attribute__((ext_vector_type(4)));

typedef const __attribute__((address_space(1))) u32 glb_u32;
typedef __attribute__((address_space(3))) u32 lds_u32;

__device__ __forceinline__ void async16(const void* g, void* l) {
    __builtin_amdgcn_global_load_lds((glb_u32*)g, (lds_u32*)l, 16, 0, 0);
}

// order-preserving float <-> uint key (unsigned compare == float compare)
__device__ __forceinline__ u32 fkey(float f) {
    u32 b = __float_as_uint(f);
    return (b & 0x80000000u) ? ~b : (b | 0x80000000u);
}
__device__ __forceinline__ float unkey(u32 k) {
    u32 b = (k & 0x80000000u) ? (k ^ 0x80000000u) : ~k;
    return __uint_as_float(b);
}

__device__ __forceinline__ u16 f2bf_rne(float f) {
    u32 b = __float_as_uint(f);
    b += 0x7FFFu + ((b >> 16) & 1u);
    return (u16)(b >> 16);
}

// DPP lane-move within 16-lane rows (reduction groups are exactly DPP rows)
template <int CTRL>
__device__ __forceinline__ float dpp_mov(float x) {
    return __int_as_float(
        __builtin_amdgcn_update_dpp(0, __float_as_int(x), CTRL, 0xF, 0xF, true));
}

// ---------------- kernel 1: fp32 -> bf16, row sum-of-squares, init keys ----------------
__global__ __launch_bounds__(256) void prep_kernel(
    const float* __restrict__ e, u16* __restrict__ ebf, float* __restrict__ sq,
    u32* __restrict__ mxk, u32* __restrict__ mnk, float* __restrict__ out) {
    const int tid = blockIdx.x * 256 + threadIdx.x;   // 2048 blocks
    const int row = tid >> 6, t = tid & 63;           // one wave per row
    float4 v = ((const float4*)(e + (size_t)row * DD))[t];
    ushort4 u;
    u.x = f2bf_rne(v.x); u.y = f2bf_rne(v.y); u.z = f2bf_rne(v.z); u.w = f2bf_rne(v.w);
    ((ushort4*)(ebf + (size_t)row * DD))[t] = u;
    float s = v.x * v.x + v.y * v.y + v.z * v.z + v.w * v.w;
    for (int o = 32; o; o >>= 1) s += __shfl_down(s, o);
    if (t == 0) {
        sq[row] = s;
        mxk[row] = 0u;            // sentinel for unsigned max
        mnk[row] = 0xFFFFFFFFu;   // sentinel for unsigned min
        if (row == 0) out[0] = 0.0f;
    }
}

// ---------------- kernel 2: barrier-free triangular dot-GEMM + two-sided reduction --------
__global__ __launch_bounds__(256, 2) void tile_kernel(
    const u16* __restrict__ ebf, const int* __restrict__ labels,
    u32* __restrict__ mxk, u32* __restrict__ mnk) {
    // full A-strip, XOR-swizzled: 16B chunk (row, c) lives at slot row*32 + (c ^ (row&31))
    __shared__ __attribute__((aligned(16))) u16 lds_a[128 * 256];   // 64 KB

    // decode linear triangle index -> (i <= j)
    const int t = blockIdx.x;
    int j = (int)((sqrtf(8.0f * (float)t + 1.0f) - 1.0f) * 0.5f);
    while ((j + 1) * (j + 2) / 2 <= t) ++j;
    while (j * (j + 1) / 2 > t) --j;
    const int i = t - j * (j + 1) / 2;
    const int bi = i * 128, bj = j * 128;

    const int tid = threadIdx.x;
    const int lane = tid & 63, wid = tid >> 6;
    const int wm = wid >> 1, wn = wid & 1;
    const int l15 = lane & 15, q = lane >> 4;

    // ---- stage A-strip: 4096 16B-chunks; instr it: wave wid covers slots (it*4+wid)*64+lane
#pragma unroll
    for (int it = 0; it < 16; ++it) {
        const int s = (it * 4 + wid) * 64 + lane;
        const int row = s >> 5, sc = s & 31, c = sc ^ (row & 31);
        async16(ebf + (size_t)(bi + row) * DD + c * 8, lds_a + (it * 4 + wid) * 512);
    }

    // B base pointers: row bj + wn*64 + ni*16 + l15, this lane's k-chunk q
    const u16* gB[4];
#pragma unroll
    for (int ni = 0; ni < 4; ++ni)
        gB[ni] = ebf + (size_t)(bj + wn * 64 + ni * 16 + l15) * DD + q * 8;

    __syncthreads();   // the ONLY barrier: A-strip DMA drained, LDS ready for everyone

    f32x4 acc[4][4] = {};
    short8 bfr[4], bnx[4];
#pragma unroll
    for (int ni = 0; ni < 4; ++ni) bfr[ni] = *(const short8*)(gB[ni]);

#pragma unroll
    for (int kt = 0; kt < 8; ++kt) {
        if (kt < 7) {
#pragma unroll
            for (int ni = 0; ni < 4; ++ni)
                bnx[ni] = *(const short8*)(gB[ni] + (kt + 1) * 32);
        }
        short8 af[4];
#pragma unroll
        for (int mi = 0; mi < 4; ++mi) {
            const int row = wm * 64 + mi * 16 + l15;
            af[mi] = *(const short8*)(lds_a + row * 256 + (((kt * 4 + q) ^ (row & 31)) * 8));
        }
#pragma unroll
        for (int mi = 0; mi < 4; ++mi)
#pragma unroll
            for (int ni = 0; ni < 4; ++ni)
                acc[mi][ni] = __builtin_amdgcn_mfma_f32_16x16x32_bf16(
                    af[mi], bfr[ni], acc[mi][ni], 0, 0, 0);
#pragma unroll
        for (int ni = 0; ni < 4; ++ni) bfr[ni] = bnx[ni];
    }

    // epilogue: C/D layout col = lane&15, row = q*4 + reg (m89-verified)
    int lj[4];
#pragma unroll
    for (int ni = 0; ni < 4; ++ni) lj[ni] = labels[bj + wn * 64 + ni * 16 + l15];

    // col-side accumulators: per (ni) -> column bj + wn*64 + ni*16 + l15
    float mxc[4] = {-BIGF, -BIGF, -BIGF, -BIGF};
    float mnc[4] = {BIGF, BIGF, BIGF, BIGF};

#pragma unroll
    for (int mi = 0; mi < 4; ++mi) {
        const int rbase = bi + wm * 64 + mi * 16 + q * 4;
        const int4 li = *(const int4*)(labels + rbase);
        float mxn[4] = {-BIGF, -BIGF, -BIGF, -BIGF};   // row-side: max dot over negatives
        float mnp[4] = {BIGF, BIGF, BIGF, BIGF};       // row-side: min dot over positives
#pragma unroll
        for (int ni = 0; ni < 4; ++ni) {
            const int l = lj[ni];
#pragma unroll
            for (int r = 0; r < 4; ++r) {
                const float d = acc[mi][ni][r];
                const int lr = (r == 0) ? li.x : (r == 1) ? li.y : (r == 2) ? li.z : li.w;
                const bool same = (lr == l);
                const float sneg = same ? -BIGF : d;
                const float spos = same ? d : BIGF;
                mxn[r] = fmaxf(mxn[r], sneg);
                mnp[r] = fminf(mnp[r], spos);
                mxc[ni] = fmaxf(mxc[ni], sneg);
                mnc[ni] = fminf(mnc[ni], spos);
            }
        }
        // row-side 16-lane reduction via DPP: xor1, xor2, ror4, ror8
#pragma unroll
        for (int r = 0; r < 4; ++r) {
            mxn[r] = fmaxf(mxn[r], dpp_mov<0xB1>(mxn[r]));
            mnp[r] = fminf(mnp[r], dpp_mov<0xB1>(mnp[r]));
            mxn[r] = fmaxf(mxn[r], dpp_mov<0x4E>(mxn[r]));
            mnp[r] = fminf(mnp[r], dpp_mov<0x4E>(mnp[r]));
            mxn[r] = fmaxf(mxn[r], dpp_mov<0x124>(mxn[r]));
            mnp[r] = fminf(mnp[r], dpp_mov<0x124>(mnp[r]));
            mxn[r] = fmaxf(mxn[r], dpp_mov<0x128>(mxn[r]));
            mnp[r] = fminf(mnp[r], dpp_mov<0x128>(mnp[r]));
        }
        if (l15 == 0) {
#pragma unroll
            for (int r = 0; r < 4; ++r) {
                atomicMax(&mxk[rbase + r], fkey(mxn[r]));
                atomicMin(&mnk[rbase + r], fkey(mnp[r]));
            }
        }
    }

    // col-side: reduce over q (lanes l15, l15+16, +32, +48) via shfl_xor 16/32
#pragma unroll
    for (int ni = 0; ni < 4; ++ni) {
        mxc[ni] = fmaxf(mxc[ni], __shfl_xor(mxc[ni], 16));
        mnc[ni] = fminf(mnc[ni], __shfl_xor(mnc[ni], 16));
        mxc[ni] = fmaxf(mxc[ni], __shfl_xor(mxc[ni], 32));
        mnc[ni] = fminf(mnc[ni], __shfl_xor(mnc[ni], 32));
    }
    if (q == 0) {
#pragma unroll
        for (int ni = 0; ni < 4; ++ni) {
            const int col = bj + wn * 64 + ni * 16 + l15;
            atomicMax(&mxk[col], fkey(mxc[ni]));
            atomicMin(&mnk[col], fkey(mnc[ni]));
        }
    }
}

// ---------------- kernel 3: per-row loss + mean ----------------
__global__ __launch_bounds__(256) void finalize_kernel(
    const u32* __restrict__ mxk, const u32* __restrict__ mnk,
    const float* __restrict__ sq, float* __restrict__ out) {
    const int i = blockIdx.x * 256 + threadIdx.x;
    const float s = sq[i] + 1.0f;   // sq_i + sq_j, sq_j = 1 +- 1e-7
    const float hn = sqrtf(fmaxf(fmaf(-2.0f, unkey(mxk[i]), s), EPS_PD));
    const float hp = sqrtf(fmaxf(fmaf(-2.0f, unkey(mnk[i]), s), EPS_PD));
    float loss = fmaxf(hp - hn + 1.0f, 0.0f);
    for (int o = 32; o; o >>= 1) loss += __shfl_down(loss, o);
    __shared__ float wsum[4];
    const int lane = threadIdx.x & 63, w = threadIdx.x >> 6;
    if (lane == 0) wsum[w] = loss;
    __syncthreads();
    if (threadIdx.x == 0)
        atomicAdd(out, (wsum[0] + wsum[1] + wsum[2] + wsum[3]) * (1.0f / NS));
}

extern "C" void kernel_launch(void* const* d_in, const int* in_sizes, int n_in,
                              void* d_out, int out_size, void* d_ws, size_t ws_size,
                              hipStream_t stream) {
    const int* labels = (const int*)d_in[0];
    const float* emb = (const float*)d_in[1];
    float* out = (float*)d_out;

    char* ws = (char*)d_ws;
    u16* ebf = (u16*)ws;                                     // 4 MB
    float* sq = (float*)(ws + (size_t)NS * DD * 2);          // 32 KB
    u32* mxk = (u32*)(ws + (size_t)NS * DD * 2 + NS * 4);
    u32* mnk = mxk + NS;

    prep_kernel<<<NS * DD / 4 / 256, 256, 0, stream>>>(emb, ebf, sq, mxk, mnk, out);
    tile_kernel<<<2080, 256, 0, stream>>>(ebf, labels, mxk, mnk);
    finalize_kernel<<<NS / 256, 256, 0, stream>>>(mxk, mnk, sq, out);
}